// Round 6
// baseline (154.893 us; speedup 1.0000x reference)
//
#include <hip/hip_runtime.h>

// SmearImages: project 64^3 voxels into 8 cameras, bilinear-sample C=3 channels,
// emit [rgb, depth, valid, viewdir] = 8 channels per (camera, voxel).
// Shapes: images [B,IP,C,H,W] f32, trans [B,IP,3,4], T_cw [B,IP,4,4],
// coords [B,3,N], out [B,IP,8,N].  B=2, IP=4, C=3, H=480, W=640, N=64^3.
#define Bc   2
#define IPc  4
#define Cc   3
#define Hc   480
#define Wc   640
#define Nc   (64 * 64 * 64)
#define CHo  8
#define VPT  4   // voxels (points) per thread; float4-wide loads/stores

typedef float f32x4 __attribute__((ext_vector_type(4)));  // clang vector: OK for nontemporal builtins

__global__ __launch_bounds__(256) void smear_images_kernel(
    const float* __restrict__ images,
    const float* __restrict__ trans,
    const float* __restrict__ tcw,
    const float* __restrict__ coords,
    float* __restrict__ out)
{
    const int bip = blockIdx.y;                 // 0..7
    const int b   = bip >> 2;                   // IP = 4
    const int n4  = (blockIdx.x * blockDim.x + threadIdx.x) * VPT;  // multiple of 4

    // ---- per-camera parameters (wave-uniform -> scalar loads) ----
    const float* __restrict__ M = trans + bip * 12;
    const float m00 = M[0],  m01 = M[1],  m02 = M[2],  m03 = M[3];
    const float m10 = M[4],  m11 = M[5],  m12 = M[6],  m13 = M[7];
    const float m20 = M[8],  m21 = M[9],  m22 = M[10], m23 = M[11];

    const float* __restrict__ T = tcw + bip * 16;
    const float r00 = T[0], r01 = T[1], r02 = T[2],  t0 = T[3];
    const float r10 = T[4], r11 = T[5], r12 = T[6],  t1 = T[7];
    const float r20 = T[8], r21 = T[9], r22 = T[10], t2 = T[11];
    // cam_center = -(R^T t)
    const float ccx = -(r00 * t0 + r10 * t1 + r20 * t2);
    const float ccy = -(r01 * t0 + r11 * t1 + r21 * t2);
    const float ccz = -(r02 * t0 + r12 * t1 + r22 * t2);

    // ---- 4 points, vectorized coord loads (16 B/lane, fully coalesced) ----
    const f32x4 pxv = *reinterpret_cast<const f32x4*>(coords + (size_t)(b * 3 + 0) * Nc + n4);
    const f32x4 pyv = *reinterpret_cast<const f32x4*>(coords + (size_t)(b * 3 + 1) * Nc + n4);
    const f32x4 pzv = *reinterpret_cast<const f32x4*>(coords + (size_t)(b * 3 + 2) * Nc + n4);

    const size_t img_base = (size_t)bip * Cc * Hc * Wc;

    float res[CHo][VPT];

    #pragma unroll
    for (int i = 0; i < VPT; ++i) {
        const float px = pxv[i], py = pyv[i], pz = pzv[i];

        // projection
        const float h0 = m00 * px + m01 * py + m02 * pz + m03;
        const float h1 = m10 * px + m11 * py + m12 * pz + m13;
        const float h2 = m20 * px + m21 * py + m22 * pz + m23;

        const float depth = h2;
        const float safe  = (fabsf(depth) > 1e-8f) ? depth : 1e-8f;
        const float u = h0 / safe;
        const float v = h1 / safe;

        const float valid = (depth > 0.0f && u >= 0.0f && u <= (float)(Wc - 1) &&
                             v >= 0.0f && v <= (float)(Hc - 1)) ? 1.0f : 0.0f;

        const float x0f = floorf(u);
        const float y0f = floorf(v);
        const float wx  = u - x0f;
        const float wy  = v - y0f;
        const int   x0  = (int)x0f;
        const int   y0  = (int)y0f;
        const int   x1  = x0 + 1;
        const int   y1  = y0 + 1;

        const float w00 = (1.0f - wx) * (1.0f - wy);
        const float w10 = wx * (1.0f - wy);
        const float w01 = (1.0f - wx) * wy;
        const float w11 = wx * wy;

        const bool ibx0 = (x0 >= 0) & (x0 < Wc);
        const bool ibx1 = (x1 >= 0) & (x1 < Wc);
        const bool iby0 = (y0 >= 0) & (y0 < Hc);
        const bool iby1 = (y1 >= 0) & (y1 < Hc);

        const int cx0 = min(max(x0, 0), Wc - 1);
        const int cx1 = min(max(x1, 0), Wc - 1);
        const int cy0 = min(max(y0, 0), Hc - 1);
        const int cy1 = min(max(y1, 0), Hc - 1);

        const int row0 = cy0 * Wc;
        const int row1 = cy1 * Wc;

        #pragma unroll
        for (int c = 0; c < Cc; ++c) {
            const float* __restrict__ img = images + img_base + (size_t)c * (Hc * Wc);
            const float v00 = (ibx0 & iby0) ? img[row0 + cx0] : 0.0f;
            const float v10 = (ibx1 & iby0) ? img[row0 + cx1] : 0.0f;
            const float v01 = (ibx0 & iby1) ? img[row1 + cx0] : 0.0f;
            const float v11 = (ibx1 & iby1) ? img[row1 + cx1] : 0.0f;
            res[c][i] = v00 * w00 + v10 * w10 + v01 * w01 + v11 * w11;
        }

        res[3][i] = depth;
        res[4][i] = valid;

        const float dx = px - ccx;
        const float dy = py - ccy;
        const float dz = pz - ccz;
        const float nrm = sqrtf(dx * dx + dy * dy + dz * dz);
        const float inv = 1.0f / fmaxf(nrm, 1e-8f);
        res[5][i] = dx * inv;
        res[6][i] = dy * inv;
        res[7][i] = dz * inv;
    }

    // ---- 8 channel-plane stores, 16 B/lane, nontemporal (write-once stream;
    // keep L2 for the image gathers) ----
    float* __restrict__ ob = out + (size_t)bip * CHo * Nc + n4;
    #pragma unroll
    for (int ch = 0; ch < CHo; ++ch) {
        f32x4 val = { res[ch][0], res[ch][1], res[ch][2], res[ch][3] };
        __builtin_nontemporal_store(val, reinterpret_cast<f32x4*>(ob + (size_t)ch * Nc));
    }
}

extern "C" void kernel_launch(void* const* d_in, const int* in_sizes, int n_in,
                              void* d_out, int out_size, void* d_ws, size_t ws_size,
                              hipStream_t stream) {
    const float* images = (const float*)d_in[0];
    const float* trans  = (const float*)d_in[1];
    const float* tcw    = (const float*)d_in[2];
    const float* coords = (const float*)d_in[3];
    float* out = (float*)d_out;

    dim3 grid(Nc / (256 * VPT), Bc * IPc);   // 256 x 8 blocks
    dim3 block(256);
    smear_images_kernel<<<grid, block, 0, stream>>>(images, trans, tcw, coords, out);
}